// Round 12
// baseline (333.738 us; speedup 1.0000x reference)
//
#include <hip/hip_runtime.h>

#define NPTS 8192
#define HDIM 64
#define KNN 16
#define LOG2E 1.4426950408889634f

typedef __attribute__((ext_vector_type(8))) short bf8_t;   // 8 bf16
typedef __attribute__((ext_vector_type(4))) float f4_t;    // MFMA C/D
#define MFMA16(a, b, c) __builtin_amdgcn_mfma_f32_16x16x32_bf16(a, b, c, 0, 0, 0)

__device__ __forceinline__ float fast_exp(float x) {
    float y = x * LOG2E;
    float r;
    asm volatile("v_exp_f32 %0, %1\n\ts_nop 1" : "=v"(r) : "v"(y));
    return r;
}
__device__ __forceinline__ unsigned short f2b(float x) {   // f32 -> bf16 RNE
    unsigned v = __float_as_uint(x);
    return (unsigned short)((v + 0x7FFFu + ((v >> 16) & 1u)) >> 16);
}

// ws layout: qw 0..4MB, kw 4..8MB, vw 8..12MB, frag 12MB..+24KB, knnIdx +32KB..+1MB
#define OFF_QW   0u
#define OFF_KW   (4u << 20)
#define OFF_VW   (8u << 20)
#define OFF_FRAG (12u << 20)
#define OFF_KNN  ((12u << 20) + 32768u)     // ws >= 14.8 MB (established R12)

// ---------------------------------------------------------------------------
// fused_pre v3: prefrag + proj + knn in ONE dispatch, NONTEMPORAL proj I/O.
// R25 post-mortem: W-amortization gained 8us (243->235); remaining 28us gap
// vs standalone knn (207) correlates with WRITE_SIZE 1MB -> 13.4MB: proj's
// q/k/v streaming stores cycle through the 4MB/XCD L2 during the whole knn
// scan, evicting xyzp candidate lines (256KB working set) and turning
// latency-critical L2 hits (~200cy) into HBM misses (~900cy). Fix: q/k/v
// stores + feat loads via __builtin_nontemporal_{store,load} (cache hint,
// bit-identical values; main kernel re-reads q/k/v from HBM/L3 anyway).
// knn path = R8/knn2 VERBATIM. Grid = 48 prefrag + triples (knn,knn,proj).
// ---------------------------------------------------------------------------
#define PRE_BLOCKS 48

__global__ __launch_bounds__(256) void fused_pre_kernel(
    const float* __restrict__ xyzp,
    const float* __restrict__ feat,
    const float* __restrict__ Wk, const float* __restrict__ bk,
    const float* __restrict__ Wq, const float* __restrict__ Wks,
    const float* __restrict__ Wv,
    const float* __restrict__ Wp2, const float* __restrict__ Wt1,
    const float* __restrict__ Wt2,
    float* __restrict__ qw, float* __restrict__ kw, float* __restrict__ vw,
    unsigned short* __restrict__ fragw,
    int* __restrict__ knnIdx)
{
    int bid = blockIdx.x;

    // ---------------- prefrag path (blocks 0..47), proven R11-R15 ----------
    if (bid < PRE_BLOCKS) {
        int i = bid * 256 + threadIdx.x;
        if (i >= 3 * 4096) return;
        int st = i >> 12, e = i & 4095;
        const float* W = (st == 0) ? Wp2 : (st == 1) ? Wt1 : Wt2;
        int k = e >> 6, n = e & 63;
        int s = k >> 5, quad = (k >> 3) & 3, j = k & 7;
        int t = n >> 4, l = quad * 16 + (n & 15);
        fragw[st * 4096 + (s * 4 + t) * 512 + l * 8 + j] = f2b(W[e]);
        return;
    }

    int j3 = bid - PRE_BLOCKS;
    int group = j3 / 3, pos = j3 - group * 3;     // groups 0..1023
    int w = threadIdx.x >> 6, lane = threadIdx.x & 63;

    // ---------------- proj path: 4 points/wave, W amortized, NT I/O --------
    if (pos == 2) {
        int p0 = group * 16 + w * 4;               // 16 points per block
        float f0 = __builtin_nontemporal_load(feat + (size_t)(p0 + 0) * HDIM + lane);
        float f1 = __builtin_nontemporal_load(feat + (size_t)(p0 + 1) * HDIM + lane);
        float f2 = __builtin_nontemporal_load(feat + (size_t)(p0 + 2) * HDIM + lane);
        float f3 = __builtin_nontemporal_load(feat + (size_t)(p0 + 3) * HDIM + lane);
        float bkl = bk[lane];
        float x0 = bkl, x1 = bkl, x2 = bkl, x3 = bkl;
        #pragma unroll 8
        for (int c = 0; c < 64; ++c) {
            float col = Wk[c * 64 + lane];
            x0 += __shfl(f0, c) * col;
            x1 += __shfl(f1, c) * col;
            x2 += __shfl(f2, c) * col;
            x3 += __shfl(f3, c) * col;
        }
        float q0 = 0.f, q1 = 0.f, q2 = 0.f, q3 = 0.f;
        float k0 = 0.f, k1 = 0.f, k2 = 0.f, k3 = 0.f;
        float v0 = 0.f, v1 = 0.f, v2 = 0.f, v3 = 0.f;
        #pragma unroll 4
        for (int c = 0; c < 64; ++c) {
            float cq = Wq[c * 64 + lane];
            float ck = Wks[c * 64 + lane];
            float cv = Wv[c * 64 + lane];
            float a0 = __shfl(x0, c), a1 = __shfl(x1, c);
            float a2 = __shfl(x2, c), a3 = __shfl(x3, c);
            q0 += a0 * cq; k0 += a0 * ck; v0 += a0 * cv;
            q1 += a1 * cq; k1 += a1 * ck; v1 += a1 * cv;
            q2 += a2 * cq; k2 += a2 * ck; v2 += a2 * cv;
            q3 += a3 * cq; k3 += a3 * ck; v3 += a3 * cv;
        }
        __builtin_nontemporal_store(q0, qw + (size_t)(p0 + 0) * HDIM + lane);
        __builtin_nontemporal_store(q1, qw + (size_t)(p0 + 1) * HDIM + lane);
        __builtin_nontemporal_store(q2, qw + (size_t)(p0 + 2) * HDIM + lane);
        __builtin_nontemporal_store(q3, qw + (size_t)(p0 + 3) * HDIM + lane);
        __builtin_nontemporal_store(k0, kw + (size_t)(p0 + 0) * HDIM + lane);
        __builtin_nontemporal_store(k1, kw + (size_t)(p0 + 1) * HDIM + lane);
        __builtin_nontemporal_store(k2, kw + (size_t)(p0 + 2) * HDIM + lane);
        __builtin_nontemporal_store(k3, kw + (size_t)(p0 + 3) * HDIM + lane);
        __builtin_nontemporal_store(v0, vw + (size_t)(p0 + 0) * HDIM + lane);
        __builtin_nontemporal_store(v1, vw + (size_t)(p0 + 1) * HDIM + lane);
        __builtin_nontemporal_store(v2, vw + (size_t)(p0 + 2) * HDIM + lane);
        __builtin_nontemporal_store(v3, vw + (size_t)(p0 + 3) * HDIM + lane);
        return;
    }

    // ---------------- knn path (R8/knn2 body VERBATIM: best knn, 207us) ----
    int wid = (group * 2 + pos) * 4 + w;  // wave id 0..8191
    int pbase = wid * 2;                 // 2 consecutive points, same batch
    int b = pbase >> 13;
    int nbase = pbase & (NPTS - 1);
    const float4* xb4 = (const float4*)xyzp + (size_t)b * NPTS;

    float qx[2], qy[2], qz[2], qs[2];
    #pragma unroll
    for (int qi = 0; qi < 2; ++qi) {
        float4 s = xb4[nbase + qi];
        qx[qi] = s.x; qy[qi] = s.y; qz[qi] = s.z;
        qs[qi] = s.x * s.x + s.y * s.y + s.z * s.z;
    }

    float dh[2][4]; int ih[2][4];
    #pragma unroll
    for (int qi = 0; qi < 2; ++qi)
        #pragma unroll
        for (int j = 0; j < 4; ++j) { dh[qi][j] = 3.4e38f; ih[qi][j] = 0x7fffffff; }

    float tau[2];
    tau[0] = 3.4e38f; tau[1] = 3.4e38f;

    #pragma unroll 1
    for (int t = 0; t < NPTS / 256; ++t) {          // 32 iters x 256 cands
        float4 c[4];
        #pragma unroll
        for (int u = 0; u < 4; ++u)
            c[u] = xb4[(t * 4 + u) * 64 + lane];
        #pragma unroll
        for (int u = 0; u < 4; ++u) {
            int m = (t * 4 + u) * 64 + lane;
            float cs = c[u].x * c[u].x + c[u].y * c[u].y + c[u].z * c[u].z;
            #pragma unroll
            for (int qi = 0; qi < 2; ++qi) {
                float d = qs[qi] + cs
                        - 2.0f * (qx[qi] * c[u].x + qy[qi] * c[u].y + qz[qi] * c[u].z);
                if (__any(d <= tau[qi])) {
                    // branchless sorted insert (strict <, ties keep lower idx)
                    bool c3 = d < dh[qi][3];
                    bool c2 = d < dh[qi][2];
                    bool c1 = d < dh[qi][1];
                    bool c0 = d < dh[qi][0];
                    dh[qi][3] = c2 ? dh[qi][2] : (c3 ? d : dh[qi][3]);
                    ih[qi][3] = c2 ? ih[qi][2] : (c3 ? m : ih[qi][3]);
                    dh[qi][2] = c1 ? dh[qi][1] : (c2 ? d : dh[qi][2]);
                    ih[qi][2] = c1 ? ih[qi][1] : (c2 ? m : ih[qi][2]);
                    dh[qi][1] = c0 ? dh[qi][0] : (c1 ? d : dh[qi][1]);
                    ih[qi][1] = c0 ? ih[qi][0] : (c1 ? m : ih[qi][1]);
                    dh[qi][0] = c0 ? d : dh[qi][0];
                    ih[qi][0] = c0 ? m : ih[qi][0];
                }
            }
        }
        if (t & 1) {
            // tau = max over 4 groups-of-16 of (min over group of dh[3]):
            // valid upper bound on final global 16th-best (proven R18)
            #pragma unroll
            for (int qi = 0; qi < 2; ++qi) {
                float t4 = dh[qi][3];
                t4 = fminf(t4, __shfl_xor(t4, 1));
                t4 = fminf(t4, __shfl_xor(t4, 2));
                t4 = fminf(t4, __shfl_xor(t4, 4));
                t4 = fminf(t4, __shfl_xor(t4, 8));
                t4 = fmaxf(t4, __shfl_xor(t4, 16));
                t4 = fmaxf(t4, __shfl_xor(t4, 32));
                tau[qi] = t4;
            }
        }
    }

    // per-qi exact top-16 extraction + full-range repair (proven R18 code,
    // qi fully unrolled: rule #20).
    #pragma unroll
    for (int qi = 0; qi < 2; ++qi) {
        int mynb = 0, head = 0;
        #pragma unroll 1
        for (int r = 0; r < KNN; ++r) {
            float d = dh[qi][0]; int i = ih[qi][0];
            #pragma unroll
            for (int s = 1; s < 64; s <<= 1) {
                float d2 = __shfl_xor(d, s); int i2 = __shfl_xor(i, s);
                if (d2 < d || (d2 == d && i2 < i)) { d = d2; i = i2; }
            }
            if (lane == r) mynb = i;
            if (ih[qi][0] == i) {
                dh[qi][0] = dh[qi][1]; ih[qi][0] = ih[qi][1];
                dh[qi][1] = dh[qi][2]; ih[qi][1] = ih[qi][2];
                dh[qi][2] = dh[qi][3]; ih[qi][2] = ih[qi][3];
                dh[qi][3] = 3.4e38f; ih[qi][3] = 0x7fffffff;
                ++head;
            }
        }
        // exact repair (proven R13-R15): ~0.7%/query
        if (__any(head >= 4)) {
            float eh[16]; int ei[16];
            #pragma unroll
            for (int j = 0; j < 16; ++j) { eh[j] = 3.4e38f; ei[j] = 0x7fffffff; }
            for (int t = 0; t < NPTS / 64; ++t) {
                int m = t * 64 + lane;
                float4 c4 = xb4[m];
                float cs = c4.x * c4.x + c4.y * c4.y + c4.z * c4.z;
                float d = qs[qi] + cs
                        - 2.0f * (qx[qi] * c4.x + qy[qi] * c4.y + qz[qi] * c4.z);
                if (d < eh[15]) {
                    eh[15] = d; ei[15] = m;
                    #pragma unroll
                    for (int j = 15; j >= 1; --j)
                        if (eh[j] < eh[j - 1]) {
                            float td = eh[j]; eh[j] = eh[j - 1]; eh[j - 1] = td;
                            int ti = ei[j]; ei[j] = ei[j - 1]; ei[j - 1] = ti;
                        }
                }
            }
            #pragma unroll 1
            for (int r = 0; r < KNN; ++r) {
                float d = eh[0]; int i = ei[0];
                #pragma unroll
                for (int s = 1; s < 64; s <<= 1) {
                    float d2 = __shfl_xor(d, s); int i2 = __shfl_xor(i, s);
                    if (d2 < d || (d2 == d && i2 < i)) { d = d2; i = i2; }
                }
                if (lane == r) mynb = i;
                if (ei[0] == i) {
                    #pragma unroll
                    for (int j = 0; j < 15; ++j) { eh[j] = eh[j + 1]; ei[j] = ei[j + 1]; }
                    eh[15] = 3.4e38f; ei[15] = 0x7fffffff;
                }
            }
        }
        mynb = min(max(mynb, 0), NPTS - 1);
        if (lane < KNN) knnIdx[(size_t)(pbase + qi) * KNN + lane] = mynb;
    }
}

// ---------------------------------------------------------------------------
// main: MFMA per-neighbor MLPs consuming knnIdx (proven verbatim R12/R14/R15).
// ---------------------------------------------------------------------------
__global__ __launch_bounds__(256) void LocalTransformer_80513456931527_kernel(
    const float* __restrict__ xyzp, const float* __restrict__ features,
    const float* __restrict__ Wp1,  const float* __restrict__ bp1,
    const float* __restrict__ bp2,  const float* __restrict__ bt1,
    const float* __restrict__ bt2,
    const float* __restrict__ Wa,   const float* __restrict__ ba,
    const float* __restrict__ qw, const float* __restrict__ kw,
    const float* __restrict__ vw,
    const unsigned short* __restrict__ fragw,
    const int* __restrict__ knnIdx,
    float* __restrict__ out)
{
    __shared__ __align__(16) float sBounce[4][16 * 68 + 4];

    int tid = threadIdx.x, w = tid >> 6, lane = tid & 63;
    int p = blockIdx.x * 4 + w;
    int b = p >> 13;
    float* bb = sBounce[w];

    int quad = lane >> 4, l15 = lane & 15;
    int mynb = knnIdx[(size_t)p * KNN + l15];
    mynb = min(max(mynb, 0), NPTS - 1);
    int nb_a = mynb;
    int nbm[4];
    #pragma unroll
    for (int r = 0; r < 4; ++r) nbm[r] = __shfl(mynb, quad * 4 + r);

    const float4 xq4 = *(const float4*)(xyzp + (size_t)p * 4);
    const float4 xn4 = *(const float4*)(xyzp + ((size_t)b * NPTS + nb_a) * 4);
    float rel0 = xq4.x - xn4.x, rel1 = xq4.y - xn4.y;
    float rel2 = xq4.z - xn4.z, rel3 = xq4.w - xn4.w;

    bf8_t pe1f[2];
    #pragma unroll
    for (int s = 0; s < 2; ++s) {
        int hb = s * 32 + quad * 8;
        float W0[8], W1[8], W2[8], W3[8], Bb[8];
        *(float4*)&W0[0] = *(const float4*)(Wp1 +       hb);
        *(float4*)&W0[4] = *(const float4*)(Wp1 +       hb + 4);
        *(float4*)&W1[0] = *(const float4*)(Wp1 +  64 + hb);
        *(float4*)&W1[4] = *(const float4*)(Wp1 +  64 + hb + 4);
        *(float4*)&W2[0] = *(const float4*)(Wp1 + 128 + hb);
        *(float4*)&W2[4] = *(const float4*)(Wp1 + 128 + hb + 4);
        *(float4*)&W3[0] = *(const float4*)(Wp1 + 192 + hb);
        *(float4*)&W3[4] = *(const float4*)(Wp1 + 192 + hb + 4);
        *(float4*)&Bb[0] = *(const float4*)(bp1 + hb);
        *(float4*)&Bb[4] = *(const float4*)(bp1 + hb + 4);
        #pragma unroll
        for (int j = 0; j < 8; ++j) {
            float a = Bb[j] + rel0 * W0[j] + rel1 * W1[j]
                            + rel2 * W2[j] + rel3 * W3[j];
            pe1f[s][j] = (short)f2b(fmaxf(a, 0.f));
        }
    }

    const bf8_t* BW = (const bf8_t*)fragw;
    f4_t pe2c[4];
    #pragma unroll
    for (int t = 0; t < 4; ++t) {
        f4_t acc = {0.f, 0.f, 0.f, 0.f};
        acc = MFMA16(pe1f[0], BW[0 * 512 + (0 * 4 + t) * 64 + lane], acc);
        acc = MFMA16(pe1f[1], BW[0 * 512 + (1 * 4 + t) * 64 + lane], acc);
        float bias = bp2[t * 16 + l15];
        #pragma unroll
        for (int r = 0; r < 4; ++r) acc[r] += bias;
        pe2c[t] = acc;
    }

    f4_t ainc[4], vpec[4];
    #pragma unroll
    for (int t = 0; t < 4; ++t) {
        float qv = qw[(size_t)p * HDIM + t * 16 + l15];
        #pragma unroll
        for (int r = 0; r < 4; ++r) {
            size_t nbo = ((size_t)b * NPTS + nbm[r]) * HDIM + t * 16 + l15;
            ainc[t][r] = qv - kw[nbo] + pe2c[t][r];
            vpec[t][r] = vw[nbo] + pe2c[t][r];
        }
    }

    #pragma unroll
    for (int t = 0; t < 4; ++t)
        #pragma unroll
        for (int r = 0; r < 4; ++r)
            bb[(quad * 4 + r) * 68 + t * 16 + l15] = ainc[t][r];
    asm volatile("s_waitcnt lgkmcnt(0)" ::: "memory");
    bf8_t af[2];
    #pragma unroll
    for (int s = 0; s < 2; ++s) {
        float tmp[8];
        *(float4*)&tmp[0] = *(const float4*)&bb[l15 * 68 + s * 32 + quad * 8];
        *(float4*)&tmp[4] = *(const float4*)&bb[l15 * 68 + s * 32 + quad * 8 + 4];
        #pragma unroll
        for (int j = 0; j < 8; ++j) af[s][j] = (short)f2b(tmp[j]);
    }

    f4_t t1c[4];
    #pragma unroll
    for (int t = 0; t < 4; ++t) {
        f4_t acc = {0.f, 0.f, 0.f, 0.f};
        acc = MFMA16(af[0], BW[1 * 512 + (0 * 4 + t) * 64 + lane], acc);
        acc = MFMA16(af[1], BW[1 * 512 + (1 * 4 + t) * 64 + lane], acc);
        float bias = bt1[t * 16 + l15];
        #pragma unroll
        for (int r = 0; r < 4; ++r) t1c[t][r] = fmaxf(acc[r] + bias, 0.f);
    }

    asm volatile("s_waitcnt lgkmcnt(0)" ::: "memory");
    #pragma unroll
    for (int t = 0; t < 4; ++t)
        #pragma unroll
        for (int r = 0; r < 4; ++r)
            bb[(quad * 4 + r) * 68 + t * 16 + l15] = t1c[t][r];
    asm volatile("s_waitcnt lgkmcnt(0)" ::: "memory");
    bf8_t tf[2];
    #pragma unroll
    for (int s = 0; s < 2; ++s) {
        float tmp[8];
        *(float4*)&tmp[0] = *(const float4*)&bb[l15 * 68 + s * 32 + quad * 8];
        *(float4*)&tmp[4] = *(const float4*)&bb[l15 * 68 + s * 32 + quad * 8 + 4];
        #pragma unroll
        for (int j = 0; j < 8; ++j) tf[s][j] = (short)f2b(tmp[j]);
    }

    f4_t lgc[4];
    #pragma unroll
    for (int t = 0; t < 4; ++t) {
        f4_t acc = {0.f, 0.f, 0.f, 0.f};
        acc = MFMA16(tf[0], BW[2 * 512 + (0 * 4 + t) * 64 + lane], acc);
        acc = MFMA16(tf[1], BW[2 * 512 + (1 * 4 + t) * 64 + lane], acc);
        float bias = bt2[t * 16 + l15];
        #pragma unroll
        for (int r = 0; r < 4; ++r) lgc[t][r] = (acc[r] + bias) * 0.125f;
    }

    float res[4];
    #pragma unroll
    for (int t = 0; t < 4; ++t) {
        float m0 = fmaxf(fmaxf(lgc[t][0], lgc[t][1]), fmaxf(lgc[t][2], lgc[t][3]));
        m0 = fmaxf(m0, __shfl_xor(m0, 16));
        m0 = fmaxf(m0, __shfl_xor(m0, 32));
        float e0 = fast_exp(lgc[t][0] - m0), e1 = fast_exp(lgc[t][1] - m0);
        float e2 = fast_exp(lgc[t][2] - m0), e3 = fast_exp(lgc[t][3] - m0);
        float sl = e0 + e1 + e2 + e3;
        float rl = e0 * vpec[t][0] + e1 * vpec[t][1]
                 + e2 * vpec[t][2] + e3 * vpec[t][3];
        sl += __shfl_xor(sl, 16); sl += __shfl_xor(sl, 32);
        rl += __shfl_xor(rl, 16); rl += __shfl_xor(rl, 32);
        res[t] = rl / sl;
    }

    float rh = (quad == 0) ? res[0] : (quad == 1) ? res[1]
             : (quad == 2) ? res[2] : res[3];
    float f = features[(size_t)p * HDIM + lane];
    float o = ba[lane];
    #pragma unroll 8
    for (int c = 0; c < 64; ++c) o += __shfl(rh, c) * Wa[c * 64 + lane];
    out[(size_t)p * HDIM + lane] = o + f;
}

// ---------------------------------------------------------------------------
extern "C" void kernel_launch(void* const* d_in, const int* in_sizes, int n_in,
                              void* d_out, int out_size, void* d_ws, size_t ws_size,
                              hipStream_t stream)
{
    (void)in_sizes; (void)n_in; (void)out_size; (void)ws_size;
    const float* xyzp     = (const float*)d_in[0];
    const float* features = (const float*)d_in[1];
    const float* Wk  = (const float*)d_in[2];
    const float* bk  = (const float*)d_in[3];
    const float* Wq  = (const float*)d_in[4];
    const float* Wks = (const float*)d_in[5];
    const float* Wv  = (const float*)d_in[6];
    const float* Wp1 = (const float*)d_in[7];
    const float* bp1 = (const float*)d_in[8];
    const float* Wp2 = (const float*)d_in[9];
    const float* bp2 = (const float*)d_in[10];
    const float* Wt1 = (const float*)d_in[11];
    const float* bt1 = (const float*)d_in[12];
    const float* Wt2 = (const float*)d_in[13];
    const float* bt2 = (const float*)d_in[14];
    const float* Wa  = (const float*)d_in[15];
    const float* ba  = (const float*)d_in[16];
    float* out = (float*)d_out;
    char* ws = (char*)d_ws;

    float* qw = (float*)(ws + OFF_QW);
    float* kw = (float*)(ws + OFF_KW);
    float* vw = (float*)(ws + OFF_VW);
    unsigned short* fragw = (unsigned short*)(ws + OFF_FRAG);
    int* knnIdx = (int*)(ws + OFF_KNN);

    fused_pre_kernel<<<PRE_BLOCKS + 3 * 1024, 256, 0, stream>>>(
        xyzp, features, Wk, bk, Wq, Wks, Wv, Wp2, Wt1, Wt2,
        qw, kw, vw, fragw, knnIdx);
    LocalTransformer_80513456931527_kernel<<<(2 * NPTS) / 4, 256, 0, stream>>>(
        xyzp, features, Wp1, bp1, bp2, bt1, bt2, Wa, ba,
        qw, kw, vw, fragw, knnIdx, out);
}

// Round 14
// 320.727 us; speedup vs baseline: 1.0406x; 1.0406x over previous
//
#include <hip/hip_runtime.h>

#define NPTS 8192
#define HDIM 64
#define KNN 16
#define LOG2E 1.4426950408889634f

typedef __attribute__((ext_vector_type(8))) short bf8_t;   // 8 bf16
typedef __attribute__((ext_vector_type(4))) float f4_t;    // MFMA C/D
#define MFMA16(a, b, c) __builtin_amdgcn_mfma_f32_16x16x32_bf16(a, b, c, 0, 0, 0)

__device__ __forceinline__ float fast_exp(float x) {
    float y = x * LOG2E;
    float r;
    asm volatile("v_exp_f32 %0, %1\n\ts_nop 1" : "=v"(r) : "v"(y));
    return r;
}
__device__ __forceinline__ unsigned short f2b(float x) {   // f32 -> bf16 RNE
    unsigned v = __float_as_uint(x);
    return (unsigned short)((v + 0x7FFFu + ((v >> 16) & 1u)) >> 16);
}

// ws layout: qw 0..4MB, kw 4..8MB, vw 8..12MB, frag 12MB..+24KB, knnIdx +32KB..+1MB
#define OFF_QW   0u
#define OFF_KW   (4u << 20)
#define OFF_VW   (8u << 20)
#define OFF_FRAG (12u << 20)
#define OFF_KNN  ((12u << 20) + 32768u)     // ws >= 14.8 MB (established R12)

// ---------------------------------------------------------------------------
// fused_pre v4 (resubmit — R13 bench was an infra failure, no data):
// phase-ordered grid — knn first, proj/prefrag in the tail.
// R26 post-mortem: NT stores bought ~7us kernel-side (235->228) but total
// was noise; remaining ~21us vs standalone knn (207) is issue-slot stealing
// from proj waves co-resident on every CU for the whole kernel (interleaved
// triples). Fix: reorder blockIdx decoding so knn = blocks [0..2047] —
// exactly machine-filling (8 blk/CU x 256 CU at VGPR48, no LDS) — proj =
// [2048..3071], prefrag = [3072..3119]. Initial resident set is PURE knn
// (standalone speed); proj/prefrag dispatch into knn's retirement tail and
// overlap it (proj at full machine ~15-20us << knn drain spread). Zero
// numeric change; dispatch order affects speed only, not correctness.
// knn body = R8/knn2 VERBATIM. proj = R25 W-amortized + R26 NT I/O.
// ---------------------------------------------------------------------------
#define KNN_BLOCKS  2048
#define PROJ_BLOCKS 1024
#define PRE_BLOCKS  48

__global__ __launch_bounds__(256) void fused_pre_kernel(
    const float* __restrict__ xyzp,
    const float* __restrict__ feat,
    const float* __restrict__ Wk, const float* __restrict__ bk,
    const float* __restrict__ Wq, const float* __restrict__ Wks,
    const float* __restrict__ Wv,
    const float* __restrict__ Wp2, const float* __restrict__ Wt1,
    const float* __restrict__ Wt2,
    float* __restrict__ qw, float* __restrict__ kw, float* __restrict__ vw,
    unsigned short* __restrict__ fragw,
    int* __restrict__ knnIdx)
{
    int bid = blockIdx.x;
    int w = threadIdx.x >> 6, lane = threadIdx.x & 63;

    if (bid >= KNN_BLOCKS) {
        int rb = bid - KNN_BLOCKS;

        // ------------- prefrag path (last 48 blocks), proven R11-R15 -------
        if (rb >= PROJ_BLOCKS) {
            int i = (rb - PROJ_BLOCKS) * 256 + threadIdx.x;
            if (i >= 3 * 4096) return;
            int st = i >> 12, e = i & 4095;
            const float* W = (st == 0) ? Wp2 : (st == 1) ? Wt1 : Wt2;
            int k = e >> 6, n = e & 63;
            int s = k >> 5, quad = (k >> 3) & 3, j = k & 7;
            int t = n >> 4, l = quad * 16 + (n & 15);
            fragw[st * 4096 + (s * 4 + t) * 512 + l * 8 + j] = f2b(W[e]);
            return;
        }

        // ------------- proj path: 4 points/wave, W amortized, NT I/O -------
        int group = rb;                            // 0..1023
        int p0 = group * 16 + w * 4;               // 16 points per block
        float f0 = __builtin_nontemporal_load(feat + (size_t)(p0 + 0) * HDIM + lane);
        float f1 = __builtin_nontemporal_load(feat + (size_t)(p0 + 1) * HDIM + lane);
        float f2 = __builtin_nontemporal_load(feat + (size_t)(p0 + 2) * HDIM + lane);
        float f3 = __builtin_nontemporal_load(feat + (size_t)(p0 + 3) * HDIM + lane);
        float bkl = bk[lane];
        float x0 = bkl, x1 = bkl, x2 = bkl, x3 = bkl;
        #pragma unroll 8
        for (int c = 0; c < 64; ++c) {
            float col = Wk[c * 64 + lane];
            x0 += __shfl(f0, c) * col;
            x1 += __shfl(f1, c) * col;
            x2 += __shfl(f2, c) * col;
            x3 += __shfl(f3, c) * col;
        }
        float q0 = 0.f, q1 = 0.f, q2 = 0.f, q3 = 0.f;
        float k0 = 0.f, k1 = 0.f, k2 = 0.f, k3 = 0.f;
        float v0 = 0.f, v1 = 0.f, v2 = 0.f, v3 = 0.f;
        #pragma unroll 4
        for (int c = 0; c < 64; ++c) {
            float cq = Wq[c * 64 + lane];
            float ck = Wks[c * 64 + lane];
            float cv = Wv[c * 64 + lane];
            float a0 = __shfl(x0, c), a1 = __shfl(x1, c);
            float a2 = __shfl(x2, c), a3 = __shfl(x3, c);
            q0 += a0 * cq; k0 += a0 * ck; v0 += a0 * cv;
            q1 += a1 * cq; k1 += a1 * ck; v1 += a1 * cv;
            q2 += a2 * cq; k2 += a2 * ck; v2 += a2 * cv;
            q3 += a3 * cq; k3 += a3 * ck; v3 += a3 * cv;
        }
        __builtin_nontemporal_store(q0, qw + (size_t)(p0 + 0) * HDIM + lane);
        __builtin_nontemporal_store(q1, qw + (size_t)(p0 + 1) * HDIM + lane);
        __builtin_nontemporal_store(q2, qw + (size_t)(p0 + 2) * HDIM + lane);
        __builtin_nontemporal_store(q3, qw + (size_t)(p0 + 3) * HDIM + lane);
        __builtin_nontemporal_store(k0, kw + (size_t)(p0 + 0) * HDIM + lane);
        __builtin_nontemporal_store(k1, kw + (size_t)(p0 + 1) * HDIM + lane);
        __builtin_nontemporal_store(k2, kw + (size_t)(p0 + 2) * HDIM + lane);
        __builtin_nontemporal_store(k3, kw + (size_t)(p0 + 3) * HDIM + lane);
        __builtin_nontemporal_store(v0, vw + (size_t)(p0 + 0) * HDIM + lane);
        __builtin_nontemporal_store(v1, vw + (size_t)(p0 + 1) * HDIM + lane);
        __builtin_nontemporal_store(v2, vw + (size_t)(p0 + 2) * HDIM + lane);
        __builtin_nontemporal_store(v3, vw + (size_t)(p0 + 3) * HDIM + lane);
        return;
    }

    // ---------------- knn path (R8/knn2 body VERBATIM: best knn, 207us) ----
    int wid = bid * 4 + w;               // wave id 0..8191
    int pbase = wid * 2;                 // 2 consecutive points, same batch
    int b = pbase >> 13;
    int nbase = pbase & (NPTS - 1);
    const float4* xb4 = (const float4*)xyzp + (size_t)b * NPTS;

    float qx[2], qy[2], qz[2], qs[2];
    #pragma unroll
    for (int qi = 0; qi < 2; ++qi) {
        float4 s = xb4[nbase + qi];
        qx[qi] = s.x; qy[qi] = s.y; qz[qi] = s.z;
        qs[qi] = s.x * s.x + s.y * s.y + s.z * s.z;
    }

    float dh[2][4]; int ih[2][4];
    #pragma unroll
    for (int qi = 0; qi < 2; ++qi)
        #pragma unroll
        for (int j = 0; j < 4; ++j) { dh[qi][j] = 3.4e38f; ih[qi][j] = 0x7fffffff; }

    float tau[2];
    tau[0] = 3.4e38f; tau[1] = 3.4e38f;

    #pragma unroll 1
    for (int t = 0; t < NPTS / 256; ++t) {          // 32 iters x 256 cands
        float4 c[4];
        #pragma unroll
        for (int u = 0; u < 4; ++u)
            c[u] = xb4[(t * 4 + u) * 64 + lane];
        #pragma unroll
        for (int u = 0; u < 4; ++u) {
            int m = (t * 4 + u) * 64 + lane;
            float cs = c[u].x * c[u].x + c[u].y * c[u].y + c[u].z * c[u].z;
            #pragma unroll
            for (int qi = 0; qi < 2; ++qi) {
                float d = qs[qi] + cs
                        - 2.0f * (qx[qi] * c[u].x + qy[qi] * c[u].y + qz[qi] * c[u].z);
                if (__any(d <= tau[qi])) {
                    // branchless sorted insert (strict <, ties keep lower idx)
                    bool c3 = d < dh[qi][3];
                    bool c2 = d < dh[qi][2];
                    bool c1 = d < dh[qi][1];
                    bool c0 = d < dh[qi][0];
                    dh[qi][3] = c2 ? dh[qi][2] : (c3 ? d : dh[qi][3]);
                    ih[qi][3] = c2 ? ih[qi][2] : (c3 ? m : ih[qi][3]);
                    dh[qi][2] = c1 ? dh[qi][1] : (c2 ? d : dh[qi][2]);
                    ih[qi][2] = c1 ? ih[qi][1] : (c2 ? m : ih[qi][2]);
                    dh[qi][1] = c0 ? dh[qi][0] : (c1 ? d : dh[qi][1]);
                    ih[qi][1] = c0 ? ih[qi][0] : (c1 ? m : ih[qi][1]);
                    dh[qi][0] = c0 ? d : dh[qi][0];
                    ih[qi][0] = c0 ? m : ih[qi][0];
                }
            }
        }
        if (t & 1) {
            // tau = max over 4 groups-of-16 of (min over group of dh[3]):
            // valid upper bound on final global 16th-best (proven R18)
            #pragma unroll
            for (int qi = 0; qi < 2; ++qi) {
                float t4 = dh[qi][3];
                t4 = fminf(t4, __shfl_xor(t4, 1));
                t4 = fminf(t4, __shfl_xor(t4, 2));
                t4 = fminf(t4, __shfl_xor(t4, 4));
                t4 = fminf(t4, __shfl_xor(t4, 8));
                t4 = fmaxf(t4, __shfl_xor(t4, 16));
                t4 = fmaxf(t4, __shfl_xor(t4, 32));
                tau[qi] = t4;
            }
        }
    }

    // per-qi exact top-16 extraction + full-range repair (proven R18 code,
    // qi fully unrolled: rule #20).
    #pragma unroll
    for (int qi = 0; qi < 2; ++qi) {
        int mynb = 0, head = 0;
        #pragma unroll 1
        for (int r = 0; r < KNN; ++r) {
            float d = dh[qi][0]; int i = ih[qi][0];
            #pragma unroll
            for (int s = 1; s < 64; s <<= 1) {
                float d2 = __shfl_xor(d, s); int i2 = __shfl_xor(i, s);
                if (d2 < d || (d2 == d && i2 < i)) { d = d2; i = i2; }
            }
            if (lane == r) mynb = i;
            if (ih[qi][0] == i) {
                dh[qi][0] = dh[qi][1]; ih[qi][0] = ih[qi][1];
                dh[qi][1] = dh[qi][2]; ih[qi][1] = ih[qi][2];
                dh[qi][2] = dh[qi][3]; ih[qi][2] = ih[qi][3];
                dh[qi][3] = 3.4e38f; ih[qi][3] = 0x7fffffff;
                ++head;
            }
        }
        // exact repair (proven R13-R15): ~0.7%/query
        if (__any(head >= 4)) {
            float eh[16]; int ei[16];
            #pragma unroll
            for (int j = 0; j < 16; ++j) { eh[j] = 3.4e38f; ei[j] = 0x7fffffff; }
            for (int t = 0; t < NPTS / 64; ++t) {
                int m = t * 64 + lane;
                float4 c4 = xb4[m];
                float cs = c4.x * c4.x + c4.y * c4.y + c4.z * c4.z;
                float d = qs[qi] + cs
                        - 2.0f * (qx[qi] * c4.x + qy[qi] * c4.y + qz[qi] * c4.z);
                if (d < eh[15]) {
                    eh[15] = d; ei[15] = m;
                    #pragma unroll
                    for (int j = 15; j >= 1; --j)
                        if (eh[j] < eh[j - 1]) {
                            float td = eh[j]; eh[j] = eh[j - 1]; eh[j - 1] = td;
                            int ti = ei[j]; ei[j] = ei[j - 1]; ei[j - 1] = ti;
                        }
                }
            }
            #pragma unroll 1
            for (int r = 0; r < KNN; ++r) {
                float d = eh[0]; int i = ei[0];
                #pragma unroll
                for (int s = 1; s < 64; s <<= 1) {
                    float d2 = __shfl_xor(d, s); int i2 = __shfl_xor(i, s);
                    if (d2 < d || (d2 == d && i2 < i)) { d = d2; i = i2; }
                }
                if (lane == r) mynb = i;
                if (ei[0] == i) {
                    #pragma unroll
                    for (int j = 0; j < 15; ++j) { eh[j] = eh[j + 1]; ei[j] = ei[j + 1]; }
                    eh[15] = 3.4e38f; ei[15] = 0x7fffffff;
                }
            }
        }
        mynb = min(max(mynb, 0), NPTS - 1);
        if (lane < KNN) knnIdx[(size_t)(pbase + qi) * KNN + lane] = mynb;
    }
}

// ---------------------------------------------------------------------------
// main: MFMA per-neighbor MLPs consuming knnIdx (proven verbatim R12/R14/R15).
// ---------------------------------------------------------------------------
__global__ __launch_bounds__(256) void LocalTransformer_80513456931527_kernel(
    const float* __restrict__ xyzp, const float* __restrict__ features,
    const float* __restrict__ Wp1,  const float* __restrict__ bp1,
    const float* __restrict__ bp2,  const float* __restrict__ bt1,
    const float* __restrict__ bt2,
    const float* __restrict__ Wa,   const float* __restrict__ ba,
    const float* __restrict__ qw, const float* __restrict__ kw,
    const float* __restrict__ vw,
    const unsigned short* __restrict__ fragw,
    const int* __restrict__ knnIdx,
    float* __restrict__ out)
{
    __shared__ __align__(16) float sBounce[4][16 * 68 + 4];

    int tid = threadIdx.x, w = tid >> 6, lane = tid & 63;
    int p = blockIdx.x * 4 + w;
    int b = p >> 13;
    float* bb = sBounce[w];

    int quad = lane >> 4, l15 = lane & 15;
    int mynb = knnIdx[(size_t)p * KNN + l15];
    mynb = min(max(mynb, 0), NPTS - 1);
    int nb_a = mynb;
    int nbm[4];
    #pragma unroll
    for (int r = 0; r < 4; ++r) nbm[r] = __shfl(mynb, quad * 4 + r);

    const float4 xq4 = *(const float4*)(xyzp + (size_t)p * 4);
    const float4 xn4 = *(const float4*)(xyzp + ((size_t)b * NPTS + nb_a) * 4);
    float rel0 = xq4.x - xn4.x, rel1 = xq4.y - xn4.y;
    float rel2 = xq4.z - xn4.z, rel3 = xq4.w - xn4.w;

    bf8_t pe1f[2];
    #pragma unroll
    for (int s = 0; s < 2; ++s) {
        int hb = s * 32 + quad * 8;
        float W0[8], W1[8], W2[8], W3[8], Bb[8];
        *(float4*)&W0[0] = *(const float4*)(Wp1 +       hb);
        *(float4*)&W0[4] = *(const float4*)(Wp1 +       hb + 4);
        *(float4*)&W1[0] = *(const float4*)(Wp1 +  64 + hb);
        *(float4*)&W1[4] = *(const float4*)(Wp1 +  64 + hb + 4);
        *(float4*)&W2[0] = *(const float4*)(Wp1 + 128 + hb);
        *(float4*)&W2[4] = *(const float4*)(Wp1 + 128 + hb + 4);
        *(float4*)&W3[0] = *(const float4*)(Wp1 + 192 + hb);
        *(float4*)&W3[4] = *(const float4*)(Wp1 + 192 + hb + 4);
        *(float4*)&Bb[0] = *(const float4*)(bp1 + hb);
        *(float4*)&Bb[4] = *(const float4*)(bp1 + hb + 4);
        #pragma unroll
        for (int j = 0; j < 8; ++j) {
            float a = Bb[j] + rel0 * W0[j] + rel1 * W1[j]
                            + rel2 * W2[j] + rel3 * W3[j];
            pe1f[s][j] = (short)f2b(fmaxf(a, 0.f));
        }
    }

    const bf8_t* BW = (const bf8_t*)fragw;
    f4_t pe2c[4];
    #pragma unroll
    for (int t = 0; t < 4; ++t) {
        f4_t acc = {0.f, 0.f, 0.f, 0.f};
        acc = MFMA16(pe1f[0], BW[0 * 512 + (0 * 4 + t) * 64 + lane], acc);
        acc = MFMA16(pe1f[1], BW[0 * 512 + (1 * 4 + t) * 64 + lane], acc);
        float bias = bp2[t * 16 + l15];
        #pragma unroll
        for (int r = 0; r < 4; ++r) acc[r] += bias;
        pe2c[t] = acc;
    }

    f4_t ainc[4], vpec[4];
    #pragma unroll
    for (int t = 0; t < 4; ++t) {
        float qv = qw[(size_t)p * HDIM + t * 16 + l15];
        #pragma unroll
        for (int r = 0; r < 4; ++r) {
            size_t nbo = ((size_t)b * NPTS + nbm[r]) * HDIM + t * 16 + l15;
            ainc[t][r] = qv - kw[nbo] + pe2c[t][r];
            vpec[t][r] = vw[nbo] + pe2c[t][r];
        }
    }

    #pragma unroll
    for (int t = 0; t < 4; ++t)
        #pragma unroll
        for (int r = 0; r < 4; ++r)
            bb[(quad * 4 + r) * 68 + t * 16 + l15] = ainc[t][r];
    asm volatile("s_waitcnt lgkmcnt(0)" ::: "memory");
    bf8_t af[2];
    #pragma unroll
    for (int s = 0; s < 2; ++s) {
        float tmp[8];
        *(float4*)&tmp[0] = *(const float4*)&bb[l15 * 68 + s * 32 + quad * 8];
        *(float4*)&tmp[4] = *(const float4*)&bb[l15 * 68 + s * 32 + quad * 8 + 4];
        #pragma unroll
        for (int j = 0; j < 8; ++j) af[s][j] = (short)f2b(tmp[j]);
    }

    f4_t t1c[4];
    #pragma unroll
    for (int t = 0; t < 4; ++t) {
        f4_t acc = {0.f, 0.f, 0.f, 0.f};
        acc = MFMA16(af[0], BW[1 * 512 + (0 * 4 + t) * 64 + lane], acc);
        acc = MFMA16(af[1], BW[1 * 512 + (1 * 4 + t) * 64 + lane], acc);
        float bias = bt1[t * 16 + l15];
        #pragma unroll
        for (int r = 0; r < 4; ++r) t1c[t][r] = fmaxf(acc[r] + bias, 0.f);
    }

    asm volatile("s_waitcnt lgkmcnt(0)" ::: "memory");
    #pragma unroll
    for (int t = 0; t < 4; ++t)
        #pragma unroll
        for (int r = 0; r < 4; ++r)
            bb[(quad * 4 + r) * 68 + t * 16 + l15] = t1c[t][r];
    asm volatile("s_waitcnt lgkmcnt(0)" ::: "memory");
    bf8_t tf[2];
    #pragma unroll
    for (int s = 0; s < 2; ++s) {
        float tmp[8];
        *(float4*)&tmp[0] = *(const float4*)&bb[l15 * 68 + s * 32 + quad * 8];
        *(float4*)&tmp[4] = *(const float4*)&bb[l15 * 68 + s * 32 + quad * 8 + 4];
        #pragma unroll
        for (int j = 0; j < 8; ++j) tf[s][j] = (short)f2b(tmp[j]);
    }

    f4_t lgc[4];
    #pragma unroll
    for (int t = 0; t < 4; ++t) {
        f4_t acc = {0.f, 0.f, 0.f, 0.f};
        acc = MFMA16(tf[0], BW[2 * 512 + (0 * 4 + t) * 64 + lane], acc);
        acc = MFMA16(tf[1], BW[2 * 512 + (1 * 4 + t) * 64 + lane], acc);
        float bias = bt2[t * 16 + l15];
        #pragma unroll
        for (int r = 0; r < 4; ++r) lgc[t][r] = (acc[r] + bias) * 0.125f;
    }

    float res[4];
    #pragma unroll
    for (int t = 0; t < 4; ++t) {
        float m0 = fmaxf(fmaxf(lgc[t][0], lgc[t][1]), fmaxf(lgc[t][2], lgc[t][3]));
        m0 = fmaxf(m0, __shfl_xor(m0, 16));
        m0 = fmaxf(m0, __shfl_xor(m0, 32));
        float e0 = fast_exp(lgc[t][0] - m0), e1 = fast_exp(lgc[t][1] - m0);
        float e2 = fast_exp(lgc[t][2] - m0), e3 = fast_exp(lgc[t][3] - m0);
        float sl = e0 + e1 + e2 + e3;
        float rl = e0 * vpec[t][0] + e1 * vpec[t][1]
                 + e2 * vpec[t][2] + e3 * vpec[t][3];
        sl += __shfl_xor(sl, 16); sl += __shfl_xor(sl, 32);
        rl += __shfl_xor(rl, 16); rl += __shfl_xor(rl, 32);
        res[t] = rl / sl;
    }

    float rh = (quad == 0) ? res[0] : (quad == 1) ? res[1]
             : (quad == 2) ? res[2] : res[3];
    float f = features[(size_t)p * HDIM + lane];
    float o = ba[lane];
    #pragma unroll 8
    for (int c = 0; c < 64; ++c) o += __shfl(rh, c) * Wa[c * 64 + lane];
    out[(size_t)p * HDIM + lane] = o + f;
}

// ---------------------------------------------------------------------------
extern "C" void kernel_launch(void* const* d_in, const int* in_sizes, int n_in,
                              void* d_out, int out_size, void* d_ws, size_t ws_size,
                              hipStream_t stream)
{
    (void)in_sizes; (void)n_in; (void)out_size; (void)ws_size;
    const float* xyzp     = (const float*)d_in[0];
    const float* features = (const float*)d_in[1];
    const float* Wk  = (const float*)d_in[2];
    const float* bk  = (const float*)d_in[3];
    const float* Wq  = (const float*)d_in[4];
    const float* Wks = (const float*)d_in[5];
    const float* Wv  = (const float*)d_in[6];
    const float* Wp1 = (const float*)d_in[7];
    const float* bp1 = (const float*)d_in[8];
    const float* Wp2 = (const float*)d_in[9];
    const float* bp2 = (const float*)d_in[10];
    const float* Wt1 = (const float*)d_in[11];
    const float* bt1 = (const float*)d_in[12];
    const float* Wt2 = (const float*)d_in[13];
    const float* bt2 = (const float*)d_in[14];
    const float* Wa  = (const float*)d_in[15];
    const float* ba  = (const float*)d_in[16];
    float* out = (float*)d_out;
    char* ws = (char*)d_ws;

    float* qw = (float*)(ws + OFF_QW);
    float* kw = (float*)(ws + OFF_KW);
    float* vw = (float*)(ws + OFF_VW);
    unsigned short* fragw = (unsigned short*)(ws + OFF_FRAG);
    int* knnIdx = (int*)(ws + OFF_KNN);

    fused_pre_kernel<<<KNN_BLOCKS + PROJ_BLOCKS + PRE_BLOCKS, 256, 0, stream>>>(
        xyzp, features, Wk, bk, Wq, Wks, Wv, Wp2, Wt1, Wt2,
        qw, kw, vw, fragw, knnIdx);
    LocalTransformer_80513456931527_kernel<<<(2 * NPTS) / 4, 256, 0, stream>>>(
        xyzp, features, Wp1, bp1, bp2, bt1, bt2, Wa, ba,
        qw, kw, vw, fragw, knnIdx, out);
}

// Round 15
// 313.095 us; speedup vs baseline: 1.0659x; 1.0244x over previous
//
#include <hip/hip_runtime.h>

#define NPTS 8192
#define HDIM 64
#define KNN 16
#define LOG2E 1.4426950408889634f

typedef __attribute__((ext_vector_type(8))) short bf8_t;   // 8 bf16
typedef __attribute__((ext_vector_type(4))) float f4_t;    // MFMA C/D
#define MFMA16(a, b, c) __builtin_amdgcn_mfma_f32_16x16x32_bf16(a, b, c, 0, 0, 0)

__device__ __forceinline__ float fast_exp(float x) {
    float y = x * LOG2E;
    float r;
    asm volatile("v_exp_f32 %0, %1\n\ts_nop 1" : "=v"(r) : "v"(y));
    return r;
}
__device__ __forceinline__ unsigned short f2b(float x) {   // f32 -> bf16 RNE
    unsigned v = __float_as_uint(x);
    return (unsigned short)((v + 0x7FFFu + ((v >> 16) & 1u)) >> 16);
}

// ws layout: qw 0..4MB, kw 4..8MB, vw 8..12MB, frag 12MB..+24KB, knnIdx +32KB..+1MB
#define OFF_QW   0u
#define OFF_KW   (4u << 20)
#define OFF_VW   (8u << 20)
#define OFF_FRAG (12u << 20)
#define OFF_KNN  ((12u << 20) + 32768u)     // ws >= 14.8 MB (established R12)

// ---------------------------------------------------------------------------
// fused_pre v5: branch-free knn scan (R1 chain x R8 grid — untested cell).
// R28 post-mortem: phase-ordering worked (fused 228->210 ~= standalone knn).
// Busy-mass audit across the session: guarded scan (R8/R22) = 313K cy/SIMD
// @63% busy; unconditional chain (R16) = 277K @56% (at HALF the grid); the
// only structure to break 65% busy was the branch-free scan (R23: 80%).
// The tau guard never cut executed VALU (fire ~87% + its own cmp/branch);
// the per-body wave-uniform branch (VALU->vcc->SALU, 1 SALU shared by 4
// SIMDs at 32 waves/CU) is the issue-rate cap. This round: UNCONDITIONAL
// cndmask insert (R16-proven exact: identity when d>=dh[3], strict <, ties
// keep lower idx) on the 2048-block 2-query/wave grid, tau machinery
// deleted. Extraction + repair + proj + prefrag + phase order unchanged.
// ---------------------------------------------------------------------------
#define KNN_BLOCKS  2048
#define PROJ_BLOCKS 1024
#define PRE_BLOCKS  48

__global__ __launch_bounds__(256) void fused_pre_kernel(
    const float* __restrict__ xyzp,
    const float* __restrict__ feat,
    const float* __restrict__ Wk, const float* __restrict__ bk,
    const float* __restrict__ Wq, const float* __restrict__ Wks,
    const float* __restrict__ Wv,
    const float* __restrict__ Wp2, const float* __restrict__ Wt1,
    const float* __restrict__ Wt2,
    float* __restrict__ qw, float* __restrict__ kw, float* __restrict__ vw,
    unsigned short* __restrict__ fragw,
    int* __restrict__ knnIdx)
{
    int bid = blockIdx.x;
    int w = threadIdx.x >> 6, lane = threadIdx.x & 63;

    if (bid >= KNN_BLOCKS) {
        int rb = bid - KNN_BLOCKS;

        // ------------- prefrag path (last 48 blocks), proven R11-R15 -------
        if (rb >= PROJ_BLOCKS) {
            int i = (rb - PROJ_BLOCKS) * 256 + threadIdx.x;
            if (i >= 3 * 4096) return;
            int st = i >> 12, e = i & 4095;
            const float* W = (st == 0) ? Wp2 : (st == 1) ? Wt1 : Wt2;
            int k = e >> 6, n = e & 63;
            int s = k >> 5, quad = (k >> 3) & 3, j = k & 7;
            int t = n >> 4, l = quad * 16 + (n & 15);
            fragw[st * 4096 + (s * 4 + t) * 512 + l * 8 + j] = f2b(W[e]);
            return;
        }

        // ------------- proj path: 4 points/wave, W amortized, NT I/O -------
        int group = rb;                            // 0..1023
        int p0 = group * 16 + w * 4;               // 16 points per block
        float f0 = __builtin_nontemporal_load(feat + (size_t)(p0 + 0) * HDIM + lane);
        float f1 = __builtin_nontemporal_load(feat + (size_t)(p0 + 1) * HDIM + lane);
        float f2 = __builtin_nontemporal_load(feat + (size_t)(p0 + 2) * HDIM + lane);
        float f3 = __builtin_nontemporal_load(feat + (size_t)(p0 + 3) * HDIM + lane);
        float bkl = bk[lane];
        float x0 = bkl, x1 = bkl, x2 = bkl, x3 = bkl;
        #pragma unroll 8
        for (int c = 0; c < 64; ++c) {
            float col = Wk[c * 64 + lane];
            x0 += __shfl(f0, c) * col;
            x1 += __shfl(f1, c) * col;
            x2 += __shfl(f2, c) * col;
            x3 += __shfl(f3, c) * col;
        }
        float q0 = 0.f, q1 = 0.f, q2 = 0.f, q3 = 0.f;
        float k0 = 0.f, k1 = 0.f, k2 = 0.f, k3 = 0.f;
        float v0 = 0.f, v1 = 0.f, v2 = 0.f, v3 = 0.f;
        #pragma unroll 4
        for (int c = 0; c < 64; ++c) {
            float cq = Wq[c * 64 + lane];
            float ck = Wks[c * 64 + lane];
            float cv = Wv[c * 64 + lane];
            float a0 = __shfl(x0, c), a1 = __shfl(x1, c);
            float a2 = __shfl(x2, c), a3 = __shfl(x3, c);
            q0 += a0 * cq; k0 += a0 * ck; v0 += a0 * cv;
            q1 += a1 * cq; k1 += a1 * ck; v1 += a1 * cv;
            q2 += a2 * cq; k2 += a2 * ck; v2 += a2 * cv;
            q3 += a3 * cq; k3 += a3 * ck; v3 += a3 * cv;
        }
        __builtin_nontemporal_store(q0, qw + (size_t)(p0 + 0) * HDIM + lane);
        __builtin_nontemporal_store(q1, qw + (size_t)(p0 + 1) * HDIM + lane);
        __builtin_nontemporal_store(q2, qw + (size_t)(p0 + 2) * HDIM + lane);
        __builtin_nontemporal_store(q3, qw + (size_t)(p0 + 3) * HDIM + lane);
        __builtin_nontemporal_store(k0, kw + (size_t)(p0 + 0) * HDIM + lane);
        __builtin_nontemporal_store(k1, kw + (size_t)(p0 + 1) * HDIM + lane);
        __builtin_nontemporal_store(k2, kw + (size_t)(p0 + 2) * HDIM + lane);
        __builtin_nontemporal_store(k3, kw + (size_t)(p0 + 3) * HDIM + lane);
        __builtin_nontemporal_store(v0, vw + (size_t)(p0 + 0) * HDIM + lane);
        __builtin_nontemporal_store(v1, vw + (size_t)(p0 + 1) * HDIM + lane);
        __builtin_nontemporal_store(v2, vw + (size_t)(p0 + 2) * HDIM + lane);
        __builtin_nontemporal_store(v3, vw + (size_t)(p0 + 3) * HDIM + lane);
        return;
    }

    // ---------------- knn path: branch-free scan (R16 chain, R22 grid) -----
    int wid = bid * 4 + w;               // wave id 0..8191
    int pbase = wid * 2;                 // 2 consecutive points, same batch
    int b = pbase >> 13;
    int nbase = pbase & (NPTS - 1);
    const float4* xb4 = (const float4*)xyzp + (size_t)b * NPTS;

    float qx[2], qy[2], qz[2], qs[2];
    #pragma unroll
    for (int qi = 0; qi < 2; ++qi) {
        float4 s = xb4[nbase + qi];
        qx[qi] = s.x; qy[qi] = s.y; qz[qi] = s.z;
        qs[qi] = s.x * s.x + s.y * s.y + s.z * s.z;
    }

    float dh[2][4]; int ih[2][4];
    #pragma unroll
    for (int qi = 0; qi < 2; ++qi)
        #pragma unroll
        for (int j = 0; j < 4; ++j) { dh[qi][j] = 3.4e38f; ih[qi][j] = 0x7fffffff; }

    #pragma unroll 1
    for (int t = 0; t < NPTS / 256; ++t) {          // 32 iters x 256 cands
        float4 c[4];
        #pragma unroll
        for (int u = 0; u < 4; ++u)
            c[u] = xb4[(t * 4 + u) * 64 + lane];
        #pragma unroll
        for (int u = 0; u < 4; ++u) {
            int m = (t * 4 + u) * 64 + lane;
            float cs = c[u].x * c[u].x + c[u].y * c[u].y + c[u].z * c[u].z;
            #pragma unroll
            for (int qi = 0; qi < 2; ++qi) {
                float d = qs[qi] + cs
                        - 2.0f * (qx[qi] * c[u].x + qy[qi] * c[u].y + qz[qi] * c[u].z);
                // unconditional branchless sorted insert (R16-proven exact:
                // identity when d >= dh[3]; strict <, ties keep lower idx)
                bool c3 = d < dh[qi][3];
                bool c2 = d < dh[qi][2];
                bool c1 = d < dh[qi][1];
                bool c0 = d < dh[qi][0];
                dh[qi][3] = c2 ? dh[qi][2] : (c3 ? d : dh[qi][3]);
                ih[qi][3] = c2 ? ih[qi][2] : (c3 ? m : ih[qi][3]);
                dh[qi][2] = c1 ? dh[qi][1] : (c2 ? d : dh[qi][2]);
                ih[qi][2] = c1 ? ih[qi][1] : (c2 ? m : ih[qi][2]);
                dh[qi][1] = c0 ? dh[qi][0] : (c1 ? d : dh[qi][1]);
                ih[qi][1] = c0 ? ih[qi][0] : (c1 ? m : ih[qi][1]);
                dh[qi][0] = c0 ? d : dh[qi][0];
                ih[qi][0] = c0 ? m : ih[qi][0];
            }
        }
    }

    // per-qi exact top-16 extraction + full-range repair (proven R18 code,
    // qi fully unrolled: rule #20).
    #pragma unroll
    for (int qi = 0; qi < 2; ++qi) {
        int mynb = 0, head = 0;
        #pragma unroll 1
        for (int r = 0; r < KNN; ++r) {
            float d = dh[qi][0]; int i = ih[qi][0];
            #pragma unroll
            for (int s = 1; s < 64; s <<= 1) {
                float d2 = __shfl_xor(d, s); int i2 = __shfl_xor(i, s);
                if (d2 < d || (d2 == d && i2 < i)) { d = d2; i = i2; }
            }
            if (lane == r) mynb = i;
            if (ih[qi][0] == i) {
                dh[qi][0] = dh[qi][1]; ih[qi][0] = ih[qi][1];
                dh[qi][1] = dh[qi][2]; ih[qi][1] = ih[qi][2];
                dh[qi][2] = dh[qi][3]; ih[qi][2] = ih[qi][3];
                dh[qi][3] = 3.4e38f; ih[qi][3] = 0x7fffffff;
                ++head;
            }
        }
        // exact repair (proven R13-R15): ~0.7%/query
        if (__any(head >= 4)) {
            float eh[16]; int ei[16];
            #pragma unroll
            for (int j = 0; j < 16; ++j) { eh[j] = 3.4e38f; ei[j] = 0x7fffffff; }
            for (int t = 0; t < NPTS / 64; ++t) {
                int m = t * 64 + lane;
                float4 c4 = xb4[m];
                float cs = c4.x * c4.x + c4.y * c4.y + c4.z * c4.z;
                float d = qs[qi] + cs
                        - 2.0f * (qx[qi] * c4.x + qy[qi] * c4.y + qz[qi] * c4.z);
                if (d < eh[15]) {
                    eh[15] = d; ei[15] = m;
                    #pragma unroll
                    for (int j = 15; j >= 1; --j)
                        if (eh[j] < eh[j - 1]) {
                            float td = eh[j]; eh[j] = eh[j - 1]; eh[j - 1] = td;
                            int ti = ei[j]; ei[j] = ei[j - 1]; ei[j - 1] = ti;
                        }
                }
            }
            #pragma unroll 1
            for (int r = 0; r < KNN; ++r) {
                float d = eh[0]; int i = ei[0];
                #pragma unroll
                for (int s = 1; s < 64; s <<= 1) {
                    float d2 = __shfl_xor(d, s); int i2 = __shfl_xor(i, s);
                    if (d2 < d || (d2 == d && i2 < i)) { d = d2; i = i2; }
                }
                if (lane == r) mynb = i;
                if (ei[0] == i) {
                    #pragma unroll
                    for (int j = 0; j < 15; ++j) { eh[j] = eh[j + 1]; ei[j] = ei[j + 1]; }
                    eh[15] = 3.4e38f; ei[15] = 0x7fffffff;
                }
            }
        }
        mynb = min(max(mynb, 0), NPTS - 1);
        if (lane < KNN) knnIdx[(size_t)(pbase + qi) * KNN + lane] = mynb;
    }
}

// ---------------------------------------------------------------------------
// main: MFMA per-neighbor MLPs consuming knnIdx (proven verbatim R12/R14/R15).
// ---------------------------------------------------------------------------
__global__ __launch_bounds__(256) void LocalTransformer_80513456931527_kernel(
    const float* __restrict__ xyzp, const float* __restrict__ features,
    const float* __restrict__ Wp1,  const float* __restrict__ bp1,
    const float* __restrict__ bp2,  const float* __restrict__ bt1,
    const float* __restrict__ bt2,
    const float* __restrict__ Wa,   const float* __restrict__ ba,
    const float* __restrict__ qw, const float* __restrict__ kw,
    const float* __restrict__ vw,
    const unsigned short* __restrict__ fragw,
    const int* __restrict__ knnIdx,
    float* __restrict__ out)
{
    __shared__ __align__(16) float sBounce[4][16 * 68 + 4];

    int tid = threadIdx.x, w = tid >> 6, lane = tid & 63;
    int p = blockIdx.x * 4 + w;
    int b = p >> 13;
    float* bb = sBounce[w];

    int quad = lane >> 4, l15 = lane & 15;
    int mynb = knnIdx[(size_t)p * KNN + l15];
    mynb = min(max(mynb, 0), NPTS - 1);
    int nb_a = mynb;
    int nbm[4];
    #pragma unroll
    for (int r = 0; r < 4; ++r) nbm[r] = __shfl(mynb, quad * 4 + r);

    const float4 xq4 = *(const float4*)(xyzp + (size_t)p * 4);
    const float4 xn4 = *(const float4*)(xyzp + ((size_t)b * NPTS + nb_a) * 4);
    float rel0 = xq4.x - xn4.x, rel1 = xq4.y - xn4.y;
    float rel2 = xq4.z - xn4.z, rel3 = xq4.w - xn4.w;

    bf8_t pe1f[2];
    #pragma unroll
    for (int s = 0; s < 2; ++s) {
        int hb = s * 32 + quad * 8;
        float W0[8], W1[8], W2[8], W3[8], Bb[8];
        *(float4*)&W0[0] = *(const float4*)(Wp1 +       hb);
        *(float4*)&W0[4] = *(const float4*)(Wp1 +       hb + 4);
        *(float4*)&W1[0] = *(const float4*)(Wp1 +  64 + hb);
        *(float4*)&W1[4] = *(const float4*)(Wp1 +  64 + hb + 4);
        *(float4*)&W2[0] = *(const float4*)(Wp1 + 128 + hb);
        *(float4*)&W2[4] = *(const float4*)(Wp1 + 128 + hb + 4);
        *(float4*)&W3[0] = *(const float4*)(Wp1 + 192 + hb);
        *(float4*)&W3[4] = *(const float4*)(Wp1 + 192 + hb + 4);
        *(float4*)&Bb[0] = *(const float4*)(bp1 + hb);
        *(float4*)&Bb[4] = *(const float4*)(bp1 + hb + 4);
        #pragma unroll
        for (int j = 0; j < 8; ++j) {
            float a = Bb[j] + rel0 * W0[j] + rel1 * W1[j]
                            + rel2 * W2[j] + rel3 * W3[j];
            pe1f[s][j] = (short)f2b(fmaxf(a, 0.f));
        }
    }

    const bf8_t* BW = (const bf8_t*)fragw;
    f4_t pe2c[4];
    #pragma unroll
    for (int t = 0; t < 4; ++t) {
        f4_t acc = {0.f, 0.f, 0.f, 0.f};
        acc = MFMA16(pe1f[0], BW[0 * 512 + (0 * 4 + t) * 64 + lane], acc);
        acc = MFMA16(pe1f[1], BW[0 * 512 + (1 * 4 + t) * 64 + lane], acc);
        float bias = bp2[t * 16 + l15];
        #pragma unroll
        for (int r = 0; r < 4; ++r) acc[r] += bias;
        pe2c[t] = acc;
    }

    f4_t ainc[4], vpec[4];
    #pragma unroll
    for (int t = 0; t < 4; ++t) {
        float qv = qw[(size_t)p * HDIM + t * 16 + l15];
        #pragma unroll
        for (int r = 0; r < 4; ++r) {
            size_t nbo = ((size_t)b * NPTS + nbm[r]) * HDIM + t * 16 + l15;
            ainc[t][r] = qv - kw[nbo] + pe2c[t][r];
            vpec[t][r] = vw[nbo] + pe2c[t][r];
        }
    }

    #pragma unroll
    for (int t = 0; t < 4; ++t)
        #pragma unroll
        for (int r = 0; r < 4; ++r)
            bb[(quad * 4 + r) * 68 + t * 16 + l15] = ainc[t][r];
    asm volatile("s_waitcnt lgkmcnt(0)" ::: "memory");
    bf8_t af[2];
    #pragma unroll
    for (int s = 0; s < 2; ++s) {
        float tmp[8];
        *(float4*)&tmp[0] = *(const float4*)&bb[l15 * 68 + s * 32 + quad * 8];
        *(float4*)&tmp[4] = *(const float4*)&bb[l15 * 68 + s * 32 + quad * 8 + 4];
        #pragma unroll
        for (int j = 0; j < 8; ++j) af[s][j] = (short)f2b(tmp[j]);
    }

    f4_t t1c[4];
    #pragma unroll
    for (int t = 0; t < 4; ++t) {
        f4_t acc = {0.f, 0.f, 0.f, 0.f};
        acc = MFMA16(af[0], BW[1 * 512 + (0 * 4 + t) * 64 + lane], acc);
        acc = MFMA16(af[1], BW[1 * 512 + (1 * 4 + t) * 64 + lane], acc);
        float bias = bt1[t * 16 + l15];
        #pragma unroll
        for (int r = 0; r < 4; ++r) t1c[t][r] = fmaxf(acc[r] + bias, 0.f);
    }

    asm volatile("s_waitcnt lgkmcnt(0)" ::: "memory");
    #pragma unroll
    for (int t = 0; t < 4; ++t)
        #pragma unroll
        for (int r = 0; r < 4; ++r)
            bb[(quad * 4 + r) * 68 + t * 16 + l15] = t1c[t][r];
    asm volatile("s_waitcnt lgkmcnt(0)" ::: "memory");
    bf8_t tf[2];
    #pragma unroll
    for (int s = 0; s < 2; ++s) {
        float tmp[8];
        *(float4*)&tmp[0] = *(const float4*)&bb[l15 * 68 + s * 32 + quad * 8];
        *(float4*)&tmp[4] = *(const float4*)&bb[l15 * 68 + s * 32 + quad * 8 + 4];
        #pragma unroll
        for (int j = 0; j < 8; ++j) tf[s][j] = (short)f2b(tmp[j]);
    }

    f4_t lgc[4];
    #pragma unroll
    for (int t = 0; t < 4; ++t) {
        f4_t acc = {0.f, 0.f, 0.f, 0.f};
        acc = MFMA16(tf[0], BW[2 * 512 + (0 * 4 + t) * 64 + lane], acc);
        acc = MFMA16(tf[1], BW[2 * 512 + (1 * 4 + t) * 64 + lane], acc);
        float bias = bt2[t * 16 + l15];
        #pragma unroll
        for (int r = 0; r < 4; ++r) lgc[t][r] = (acc[r] + bias) * 0.125f;
    }

    float res[4];
    #pragma unroll
    for (int t = 0; t < 4; ++t) {
        float m0 = fmaxf(fmaxf(lgc[t][0], lgc[t][1]), fmaxf(lgc[t][2], lgc[t][3]));
        m0 = fmaxf(m0, __shfl_xor(m0, 16));
        m0 = fmaxf(m0, __shfl_xor(m0, 32));
        float e0 = fast_exp(lgc[t][0] - m0), e1 = fast_exp(lgc[t][1] - m0);
        float e2 = fast_exp(lgc[t][2] - m0), e3 = fast_exp(lgc[t][3] - m0);
        float sl = e0 + e1 + e2 + e3;
        float rl = e0 * vpec[t][0] + e1 * vpec[t][1]
                 + e2 * vpec[t][2] + e3 * vpec[t][3];
        sl += __shfl_xor(sl, 16); sl += __shfl_xor(sl, 32);
        rl += __shfl_xor(rl, 16); rl += __shfl_xor(rl, 32);
        res[t] = rl / sl;
    }

    float rh = (quad == 0) ? res[0] : (quad == 1) ? res[1]
             : (quad == 2) ? res[2] : res[3];
    float f = features[(size_t)p * HDIM + lane];
    float o = ba[lane];
    #pragma unroll 8
    for (int c = 0; c < 64; ++c) o += __shfl(rh, c) * Wa[c * 64 + lane];
    out[(size_t)p * HDIM + lane] = o + f;
}

// ---------------------------------------------------------------------------
extern "C" void kernel_launch(void* const* d_in, const int* in_sizes, int n_in,
                              void* d_out, int out_size, void* d_ws, size_t ws_size,
                              hipStream_t stream)
{
    (void)in_sizes; (void)n_in; (void)out_size; (void)ws_size;
    const float* xyzp     = (const float*)d_in[0];
    const float* features = (const float*)d_in[1];
    const float* Wk  = (const float*)d_in[2];
    const float* bk  = (const float*)d_in[3];
    const float* Wq  = (const float*)d_in[4];
    const float* Wks = (const float*)d_in[5];
    const float* Wv  = (const float*)d_in[6];
    const float* Wp1 = (const float*)d_in[7];
    const float* bp1 = (const float*)d_in[8];
    const float* Wp2 = (const float*)d_in[9];
    const float* bp2 = (const float*)d_in[10];
    const float* Wt1 = (const float*)d_in[11];
    const float* bt1 = (const float*)d_in[12];
    const float* Wt2 = (const float*)d_in[13];
    const float* bt2 = (const float*)d_in[14];
    const float* Wa  = (const float*)d_in[15];
    const float* ba  = (const float*)d_in[16];
    float* out = (float*)d_out;
    char* ws = (char*)d_ws;

    float* qw = (float*)(ws + OFF_QW);
    float* kw = (float*)(ws + OFF_KW);
    float* vw = (float*)(ws + OFF_VW);
    unsigned short* fragw = (unsigned short*)(ws + OFF_FRAG);
    int* knnIdx = (int*)(ws + OFF_KNN);

    fused_pre_kernel<<<KNN_BLOCKS + PROJ_BLOCKS + PRE_BLOCKS, 256, 0, stream>>>(
        xyzp, features, Wk, bk, Wq, Wks, Wv, Wp2, Wt1, Wt2,
        qw, kw, vw, fragw, knnIdx);
    LocalTransformer_80513456931527_kernel<<<(2 * NPTS) / 4, 256, 0, stream>>>(
        xyzp, features, Wp1, bp1, bp2, bt1, bt2, Wa, ba,
        qw, kw, vw, fragw, knnIdx, out);
}